// Round 7
// baseline (333.065 us; speedup 1.0000x reference)
//
#include <hip/hip_runtime.h>
#include <hip/hip_bf16.h>
#include <math.h>

// Problem constants
#define N_ROUTES 7
#define PC_DIM   512
#define MC_DIM   128
#define KCLS     25
#define BATCH    4096

#define ROW_IN   (N_ROUTES * PC_DIM)          // 3584 elems per batch row of pose
#define JDIM     (KCLS * MC_DIM)              // 3200 vote cols per route
#define VOTE_B   (N_ROUTES * JDIM)            // 22400 vote elems per batch elem

typedef __attribute__((ext_vector_type(8))) _Float16 half8;
typedef __attribute__((ext_vector_type(4))) float f32x4;

__device__ inline ushort f2h(float f) {
    _Float16 h = (_Float16)f;
    return __builtin_bit_cast(ushort, h);
}

__device__ inline float2 h2f2(uint u) {
    union { uint x; _Float16 h[2]; } c; c.x = u;
    return make_float2((float)c.h[0], (float)c.h[1]);
}

__device__ inline void load_lds16(const void* g, void* l) {
    __builtin_amdgcn_global_load_lds(
        (const __attribute__((address_space(1))) void*)g,
        (__attribute__((address_space(3))) void*)l, 16, 0, 0);
}

// ---------------- conversion kernels ----------------
__global__ __launch_bounds__(256) void conv_pose(const float* __restrict__ p,
                                                 ushort* __restrict__ pb, int n8) {
    int i = blockIdx.x * 256 + threadIdx.x;
    if (i >= n8) return;
    const float4* s = (const float4*)p + (size_t)i * 2;
    float4 a = s[0], b = s[1];
    ushort t[8];
    t[0]=f2h(a.x); t[1]=f2h(a.y); t[2]=f2h(a.z); t[3]=f2h(a.w);
    t[4]=f2h(b.x); t[5]=f2h(b.y); t[6]=f2h(b.z); t[7]=f2h(b.w);
    *(uint4*)(pb + (size_t)i * 8) = *(uint4*)t;
}

// w fp32 [7][512][3200] -> wt fp16 [7][3200][512] (transposed per route).
// 32j x 64d tile; each output j-row written as a FULL 128B line (8 thr x uint4).
// LDS stride 65 floats keeps both phases conflict-free.
__global__ __launch_bounds__(256) void conv_w(const float* __restrict__ w,
                                              ushort* __restrict__ wt) {
    __shared__ float t[32][65];
    const int j0 = blockIdx.x * 32, d0 = blockIdx.y * 64, r = blockIdx.z;
    const int jc = threadIdx.x & 31, dr0 = threadIdx.x >> 5;   // 8 d-rows/pass
    const float* wp = w + (size_t)r * PC_DIM * JDIM;
#pragma unroll
    for (int i = 0; i < 8; i++)
        t[jc][dr0 + i * 8] = wp[(size_t)(d0 + dr0 + i * 8) * JDIM + j0 + jc];
    __syncthreads();
    const int jr = threadIdx.x >> 3, dc = (threadIdx.x & 7) * 8;
    ushort o[8];
#pragma unroll
    for (int k = 0; k < 8; k++) o[k] = f2h(t[jr][dc + k]);
    ushort* op = wt + (size_t)r * JDIM * PC_DIM;
    *(uint4*)(op + (size_t)(j0 + jr) * PC_DIM + d0 + dc) = *(uint4*)o;
}

// ---------------- Kernel 1: MFMA vote GEMM (fp16 in, fp16 out) ----------------
// r13: register-level fragment double-buffer. r8-r12 all had the SAME defect:
// tile t's MFMAs consume tile t's ds_reads -> per-tile serial chain
// (ds_read latency + barrier join) that 2-3 blocks/CU cannot hide; MfmaUtil
// pinned 28-33% across all shapes while BOTH pipes sat <50% busy. Now: compute
// tile t from regset X while reading tile t+1 into regset Y -- the MFMA burst
// depends only on LAST iteration's reads, so ds_read latency hides under MFMA
// issue. Geometry = r10 (128x128 block, 4 waves 2Mx2N, wave tile 64x64,
// acc[4][4]=64 regs, BK=32, 3-deep LDS rotation 48KB -> 3 blocks/CU):
// the 64-reg acc leaves room for 2x32 frag regs (~165 total, 3 waves/SIMD).
// Counted vmcnt(4) (never 0 until drain), ONE barrier per K-tile, no lgkm pins
// (r12 lesson). XOR swizzle + FETCH-verified XCD map unchanged.

#define BAR() do { __builtin_amdgcn_sched_barrier(0); \
                   __builtin_amdgcn_s_barrier(); \
                   __builtin_amdgcn_sched_barrier(0); } while (0)
#define WAIT_VM(n) do { asm volatile("s_waitcnt vmcnt(" #n ")" ::: "memory"); } while (0)

__global__ __launch_bounds__(256, 3) void vote_gemm_mfma(
        const ushort* __restrict__ poseb,  // [rows][3584] fp16
        const ushort* __restrict__ wt,     // [7][3200][512] fp16
        ushort* __restrict__ vote,         // [rows][7][3200] fp16
        int rows) {
    __shared__ __align__(16) char smem[49152];   // 3 bufs x (A 8KB | B 8KB)

    int route, rowTile, jTile;
    {
        const int blk = blockIdx.x;
        if (gridDim.x == 5600) {           // full batch: 32 rowTiles x 7 x 25
            const int x = blk & 7;         // XCD id (perf heuristic only)
            const int g = blk >> 3;        // 0..699
            const int q = g / 25;          // 0..27
            jTile = g - q * 25;
            const int p = x * 28 + q;      // 0..223 = route*32 + rowTile
            route = p >> 5;
            rowTile = p & 31;
        } else {
            rowTile = blk / 175;
            const int rem = blk - rowTile * 175;
            route = rem / 25;
            jTile = rem - route * 25;
        }
    }
    const int b0 = rowTile * 128;
    const int j0 = jTile * 128;

    const int tid = threadIdx.x;
    const int l = tid & 63, w = tid >> 6;
    const int wm = w >> 1, wn = w & 1;     // 2 M-waves x 2 N-waves
    const int lm = l & 15, q4 = l >> 4;
    const int xr = (l >> 1) & 3;           // == ((row>>1)&3) for row = 16k + lm

    const ushort* Aptr = poseb + (size_t)route * PC_DIM;
    const ushort* Bptr = wt + (size_t)route * JDIM * PC_DIM;

    // Staging source offsets (elements). 512 chunks of 8 fp16 per operand tile;
    // chunk f: row = f>>2, c = f&3, pre-swizzled source col-group qg = c^((row>>1)&3).
    uint aof0, aof1, bof0, bof1;
    {
        int f, row, c, qg, ga;
        f = tid;        row = f >> 2; c = f & 3; qg = c ^ ((row >> 1) & 3);
        ga = b0 + row; if (ga >= rows) ga = rows - 1;
        aof0 = (uint)ga * ROW_IN + qg * 8;
        bof0 = (uint)(j0 + row) * PC_DIM + qg * 8;      // j0+row <= 3199 always
        f = tid + 256;  row = f >> 2; c = f & 3; qg = c ^ ((row >> 1) & 3);
        ga = b0 + row; if (ga >= rows) ga = rows - 1;
        aof1 = (uint)ga * ROW_IN + qg * 8;
        bof1 = (uint)(j0 + row) * PC_DIM + qg * 8;
    }

    // LDS byte offsets of this lane's fragments (swizzled read side).
    // A section at buf+0, B at buf+8192; row addr = (row*4 + pos)*16.
    const int aBase = ((wm * 64 + lm) * 4 + (q4 ^ xr)) * 16;           // + mt*1024
    const int bBase = 8192 + ((wn * 64 + lm) * 4 + (q4 ^ xr)) * 16;    // + nt*1024

    f32x4 acc[4][4] = {};

#define STAGE(kt) do { \
        char* d_ = smem + (((kt) % 3) * 16384); \
        load_lds16(Aptr + aof0 + (kt) * 32, d_ + (size_t)tid * 16); \
        load_lds16(Aptr + aof1 + (kt) * 32, d_ + (size_t)(tid + 256) * 16); \
        load_lds16(Bptr + bof0 + (kt) * 32, d_ + 8192 + (size_t)tid * 16); \
        load_lds16(Bptr + bof1 + (kt) * 32, d_ + 8192 + (size_t)(tid + 256) * 16); \
    } while (0)

#define READF(kt, AF, BF) do { \
        const char* rp_ = smem + (((kt) % 3) * 16384); \
        _Pragma("unroll") for (int i_ = 0; i_ < 4; i_++) { \
            AF[i_] = *(const half8*)(rp_ + aBase + i_ * 1024); \
            BF[i_] = *(const half8*)(rp_ + bBase + i_ * 1024); \
        } \
    } while (0)

#define MFMA16(AF, BF) do { \
        _Pragma("unroll") for (int mt_ = 0; mt_ < 4; mt_++) \
        _Pragma("unroll") for (int nt_ = 0; nt_ < 4; nt_++) \
            acc[mt_][nt_] = __builtin_amdgcn_mfma_f32_16x16x32_f16( \
                AF[mt_], BF[nt_], acc[mt_][nt_], 0, 0, 0); \
    } while (0)

    // Prologue: stage 0,1; wait tile0 (4 of 8 outstanding); preload frags(0)->X.
    STAGE(0); STAGE(1);
    WAIT_VM(4);
    BAR();
    half8 ax[4], bx[4], ay[4], by[4];
    READF(0, ax, bx);
    STAGE(2);                              // outstanding: t1(4) + t2(4)

    // Steady state: per half-step {vmcnt(4) -> barrier -> read t+1 into other
    // set || stage t+3 || 16 MFMA on current set}. MFMAs never wait on this
    // half-step's ds_reads.
#pragma unroll
    for (int tt = 0; tt < 7; ++tt) {
        const int t = 2 * tt;
        WAIT_VM(4);                        // tile t+1 landed (t+2 in flight)
        BAR();                             // all waves' t+1 DMAs visible
        READF(t + 1, ay, by);
        STAGE(t + 3);
        MFMA16(ax, bx);                    // tile t (regset X, read last half-step)
        WAIT_VM(4);                        // tile t+2 landed
        BAR();
        READF(t + 2, ax, bx);
        if (t + 4 <= 15) STAGE(t + 4);
        MFMA16(ay, by);                    // tile t+1
    }
    // Loop computed tiles 0..13; X holds frags(14); tile15 loads outstanding.
    WAIT_VM(0);
    BAR();
    READF(15, ay, by);
    MFMA16(ax, bx);                        // tile 14
    MFMA16(ay, by);                        // tile 15
    BAR();                                 // all frag reads done before smem reuse

    // Epilogue: per-wave LDS transpose, double-region (no trailing wait).
    const int erow = l >> 2, ec0 = (l & 3) * 16;
#pragma unroll
    for (int mt = 0; mt < 4; mt++) {
        float* ep = (float*)smem + w * 1088 + (mt & 1) * 4352;
#pragma unroll
        for (int nt = 0; nt < 4; nt++)
#pragma unroll
            for (int i = 0; i < 4; i++)
                ep[(q4 * 4 + i) * 68 + nt * 16 + lm] = acc[mt][nt][i];
        asm volatile("s_waitcnt lgkmcnt(0)" ::: "memory");
        const int grow = b0 + wm * 64 + mt * 16 + erow;
        if (grow < rows) {
            ushort t16[16];
#pragma unroll
            for (int t8 = 0; t8 < 4; t8++) {
                float4 v = *(float4*)&ep[erow * 68 + ec0 + t8 * 4];
                t16[t8*4+0]=f2h(v.x); t16[t8*4+1]=f2h(v.y);
                t16[t8*4+2]=f2h(v.z); t16[t8*4+3]=f2h(v.w);
            }
            ushort* dst = vote + (size_t)grow * VOTE_B + route * JDIM + j0 + wn * 64 + ec0;
            ((uint4*)dst)[0] = ((uint4*)t16)[0];
            ((uint4*)dst)[1] = ((uint4*)t16)[1];
        }
    }
}

// ---------------- Kernel 2: fused routing ----------------
// Block = one batch elem, 448 threads (7 waves). Lane decomposition:
//   sub = l&15 -> v-dims [8*sub, 8*sub+8);  mg = l>>4;  m = wv + 7*mg (28 slots, 25 valid).
// Votes unpacked ONCE to 56 fp32 regs. Reductions: 4-step shfl over 16 lanes.
__global__ __launch_bounds__(448) void routing_kernel(
        const ushort* __restrict__ vote16,  // [chunk][7][25][128] fp16
        const float* __restrict__ act,      // (pre-offset)
        const float* __restrict__ gamma,
        const float* __restrict__ beta,
        const float* __restrict__ emb,      // [25,128]
        const float* __restrict__ bias,     // [25]
        float* __restrict__ out_logits,
        float* __restrict__ out_act,
        float* __restrict__ out_coef) {
    const int b = blockIdx.x;
    __shared__ float coef_s[N_ROUTES * KCLS];
    __shared__ float act_s[8];

    const int tid = threadIdx.x, l = tid & 63, wv = tid >> 6;   // 7 waves
    const int sub = l & 15, mg = l >> 4;
    const int m = wv + 7 * mg;                // 0..27
    const bool mv = (m < KCLS);

    if (tid < N_ROUTES) {
        float a = act[(size_t)b * N_ROUTES + tid];
        act_s[tid] = a;
        out_act[(size_t)b * N_ROUTES + tid] = a;
    }

    // Load votes (coalesced 16B) and unpack to fp32 ONCE.
    float vf[N_ROUTES][8];
    if (mv) {
        const uint4* vb = (const uint4*)(vote16 + (size_t)b * VOTE_B);  // n*400 + m*16 + sub
#pragma unroll
        for (int n = 0; n < N_ROUTES; n++) {
            uint4 q = vb[n * 400 + m * 16 + sub];
            float2 f0 = h2f2(q.x), f1 = h2f2(q.y), f2 = h2f2(q.z), f3 = h2f2(q.w);
            vf[n][0] = f0.x; vf[n][1] = f0.y; vf[n][2] = f1.x; vf[n][3] = f1.y;
            vf[n][4] = f2.x; vf[n][5] = f2.y; vf[n][6] = f3.x; vf[n][7] = f3.y;
        }
    } else {
#pragma unroll
        for (int n = 0; n < N_ROUTES; n++)
#pragma unroll
            for (int j = 0; j < 8; j++) vf[n][j] = 0.f;
    }
    const int mc = mv ? m : 24;

    float g[8], be[8];
    *(float4*)(g)      = *(const float4*)(gamma + 8 * sub);
    *(float4*)(g + 4)  = *(const float4*)(gamma + 8 * sub + 4);
    *(float4*)(be)     = *(const float4*)(beta  + 8 * sub);
    *(float4*)(be + 4) = *(const float4*)(beta  + 8 * sub + 4);
    __syncthreads();   // act_s ready

    const float scale = 0.088388347648318447f;    // 1/sqrt(128)
    float pose[8];

    auto update = [&](bool first) {
        float r[8];
#pragma unroll
        for (int j = 0; j < 8; j++) r[j] = 0.f;
#pragma unroll
        for (int n = 0; n < N_ROUTES; n++) {
            float c = first ? (act_s[n] * 0.04f) : (coef_s[n * KCLS + mc] * act_s[n]);
#pragma unroll
            for (int j = 0; j < 8; j++) r[j] += c * vf[n][j];
        }
        float S = 0.f, Q = 0.f;
#pragma unroll
        for (int j = 0; j < 8; j++) { S += r[j]; Q += r[j] * r[j]; }
#pragma unroll
        for (int o = 8; o; o >>= 1) {
            S += __shfl_xor(S, o);
            Q += __shfl_xor(Q, o);
        }
        float mean = S * 0.0078125f;
        float var  = Q * 0.0078125f - mean * mean;
        float rs   = rsqrtf(var + 1e-5f);
#pragma unroll
        for (int j = 0; j < 8; j++) pose[j] = (r[j] - mean) * rs * g[j] + be[j];
    };

    update(true);
    __syncthreads();

    const int sgrp = tid >> 5, slane = tid & 31;   // 14 x 32-lane groups for softmax

    for (int it = 1; it < 3; it++) {
        // agreement: d[n] = <vote[n][m], pose[m]>
        float d[N_ROUTES];
#pragma unroll
        for (int n = 0; n < N_ROUTES; n++) {
            float t = 0.f;
#pragma unroll
            for (int j = 0; j < 8; j++) t += vf[n][j] * pose[j];
            d[n] = t;
        }
#pragma unroll
        for (int o = 8; o; o >>= 1)
#pragma unroll
            for (int n = 0; n < N_ROUTES; n++) d[n] += __shfl_xor(d[n], o);
        if (sub == 0 && mv) {
#pragma unroll
            for (int n = 0; n < N_ROUTES; n++) coef_s[n * KCLS + m] = d[n] * scale;
        }
        __syncthreads();
        // parallel softmax: group sgrp = route, lane slane = m
        if (sgrp < N_ROUTES) {
            float c = (slane < KCLS) ? coef_s[sgrp * KCLS + slane] : -1e30f;
            float mx = c;
#pragma unroll
            for (int o = 16; o; o >>= 1) mx = fmaxf(mx, __shfl_xor(mx, o, 32));
            float e = (slane < KCLS) ? expf(c - mx) : 0.f;
            float s = e;
#pragma unroll
            for (int o = 16; o; o >>= 1) s += __shfl_xor(s, o, 32);
            if (slane < KCLS) coef_s[sgrp * KCLS + slane] = e / s;
        }
        __syncthreads();
        update(false);
        if (it == 1) __syncthreads();   // coef_s reads done before next agree overwrites
    }

    // logits
    float e[8];
    *(float4*)(e)     = *(const float4*)(emb + mc * MC_DIM + 8 * sub);
    *(float4*)(e + 4) = *(const float4*)(emb + mc * MC_DIM + 8 * sub + 4);
    float dd = 0.f;
#pragma unroll
    for (int j = 0; j < 8; j++) dd += pose[j] * e[j];
#pragma unroll
    for (int o = 8; o; o >>= 1) dd += __shfl_xor(dd, o);
    if (sub == 0 && mv) out_logits[(size_t)b * KCLS + m] = dd + bias[m];

    if (tid < N_ROUTES * KCLS)
        out_coef[(size_t)b * (N_ROUTES * KCLS) + tid] = coef_s[tid];
}

// ---------------- launch ----------------
extern "C" void kernel_launch(void* const* d_in, const int* in_sizes, int n_in,
                              void* d_out, int out_size, void* d_ws, size_t ws_size,
                              hipStream_t stream) {
    const float* pose  = (const float*)d_in[0];
    const float* act   = (const float*)d_in[1];
    const float* w     = (const float*)d_in[2];
    const float* gamma = (const float*)d_in[3];
    const float* beta  = (const float*)d_in[4];
    const float* emb   = (const float*)d_in[5];
    const float* bias  = (const float*)d_in[6];

    float* out        = (float*)d_out;
    float* out_logits = out;
    float* out_act    = out + BATCH * KCLS;
    float* out_coef   = out + BATCH * KCLS + BATCH * N_ROUTES;

    // workspace: wt fp16 | poseb fp16 | vote fp16 (chunked)
    const size_t wt_bytes    = (size_t)N_ROUTES * JDIM * PC_DIM * 2;
    const size_t poseb_bytes = (size_t)BATCH * ROW_IN * 2;
    ushort* wt    = (ushort*)d_ws;
    ushort* poseb = (ushort*)((char*)d_ws + wt_bytes);
    ushort* voteh = (ushort*)((char*)d_ws + wt_bytes + poseb_bytes);

    size_t rem = ws_size > wt_bytes + poseb_bytes ? ws_size - wt_bytes - poseb_bytes : 0;
    size_t cap = rem / ((size_t)VOTE_B * 2);
    int chunk;
    if (cap >= (size_t)BATCH)  chunk = BATCH;   // single dispatch: deepest grid, no tail split
    else if (cap >= 128)       chunk = (int)(cap & ~(size_t)127);
    else                       chunk = (int)(cap > 0 ? cap : 1);

    conv_w<<<dim3(JDIM / 32, PC_DIM / 64, N_ROUTES), 256, 0, stream>>>(w, wt);
    const int n8 = BATCH * ROW_IN / 8;
    conv_pose<<<(n8 + 255) / 256, 256, 0, stream>>>(pose, poseb, n8);

    for (int b0 = 0; b0 < BATCH; b0 += chunk) {
        int rows = BATCH - b0 < chunk ? BATCH - b0 : chunk;
        int nRowTiles = (rows + 127) / 128;
        vote_gemm_mfma<<<nRowTiles * 175, 256, 0, stream>>>(
            poseb + (size_t)b0 * ROW_IN, wt, voteh, rows);
        routing_kernel<<<rows, 448, 0, stream>>>(
            voteh,
            act + (size_t)b0 * N_ROUTES,
            gamma, beta, emb, bias,
            out_logits + (size_t)b0 * KCLS,
            out_act    + (size_t)b0 * N_ROUTES,
            out_coef   + (size_t)b0 * N_ROUTES * KCLS);
    }
}